// Round 4
// baseline (565.156 us; speedup 1.0000x reference)
//
#include <hip/hip_runtime.h>
#include <hip/hip_bf16.h>
#include <cstdint>
#include <cstddef>

#define NROWS 32768
#define NCLS  1000
#define KP    1024   // padded class dim
#define NCH   32     // k-chunks per panel (KP/32)

typedef unsigned short u16;
typedef __bf16 bf16x8 __attribute__((ext_vector_type(8)));
typedef float  f32x4  __attribute__((ext_vector_type(4)));

// Fragment-chunk layout ("X4"): matrix [Rows][KP] stored as
//   chunk(R, c) = 1KB block at ((R*NCH)+c)*512 halfwords, R = row/16, c = k/32
//   slot l (l=0..63, 16B) = elements [R*16 + (l&15)][c*32 + (l>>4)*8 + j], j=0..7
// => staging global loads, global_load_lds lane scatter, LDS fragment reads,
//    and MFMA A/B operand layout (m=lane&15, k=(lane>>4)*8+j) are ALL base+lane*16.

__device__ __forceinline__ void gld_lds16(const u16* g, u16* l) {
  __builtin_amdgcn_global_load_lds(
      (const __attribute__((address_space(1))) unsigned int*)g,
      (__attribute__((address_space(3))) unsigned int*)l, 16, 0, 0);
}

// ---- prep: bank f32 [1000x1000] -> M4 and MT4 (fragment-chunk, zero-padded to 1024)
__global__ __launch_bounds__(128)
void prep4_bank(const float* __restrict__ bank,
                __hip_bfloat16* __restrict__ M4,
                __hip_bfloat16* __restrict__ MT4) {
  __shared__ float tile[32][33];
  const int tx = blockIdx.x;  // col chunk (k)
  const int ty = blockIdx.y;  // row chunk (j)
  const int t  = threadIdx.x;
  {
    const int r = t >> 2, c0 = (t & 3) * 8;
    const int gj = ty * 32 + r;
    #pragma unroll
    for (int j = 0; j < 8; ++j) {
      const int gk = tx * 32 + c0 + j;
      tile[r][c0 + j] = (gj < NCLS && gk < NCLS) ? bank[gj * NCLS + gk] : 0.0f;
    }
  }
  __syncthreads();
  const int w = t >> 6, lane = t & 63, lr = lane & 15, qq = lane >> 4;
  if (w == 0) {
    #pragma unroll
    for (int s = 0; s < 2; ++s) {
      bf16x8 o;
      #pragma unroll
      for (int j = 0; j < 8; ++j) o[j] = (__bf16)tile[s * 16 + lr][qq * 8 + j];
      *(bf16x8*)((u16*)M4 + ((size_t)(ty * 2 + s) * NCH + tx) * 512 + lane * 8) = o;
    }
  } else {
    #pragma unroll
    for (int s = 0; s < 2; ++s) {
      bf16x8 o;
      #pragma unroll
      for (int j = 0; j < 8; ++j) o[j] = (__bf16)tile[qq * 8 + j][s * 16 + lr];
      *(bf16x8*)((u16*)MT4 + ((size_t)(tx * 2 + s) * NCH + ty) * 512 + lane * 8) = o;
    }
  }
}

// ---- fused: p_tar -> A4 (fragment-chunk bf16), argmax agreement + segment-sum atomics
// NEW: one 16-row panel per BLOCK; the 4 waves k-split the 32 chunks (8 each)
// -> 2048 blocks x 4 waves = 32 waves/CU (was 8) to hide the strided-load latency.
// Partial argmax per wave combined through LDS; first-occurrence ties preserved
// (within-wave: index-min on equal; across waves: ascending k-range, strict >).
__global__ __launch_bounds__(256)
void rows4_kernel(const float* __restrict__ p_tar, const float* __restrict__ p_vlm,
                  __hip_bfloat16* __restrict__ A4,
                  float* __restrict__ sums, float* __restrict__ counts) {
  __shared__ float sT[4][16]; __shared__ int siT[4][16];
  __shared__ float sV[4][16]; __shared__ int siV[4][16];
  const int w = threadIdx.x >> 6, lane = threadIdx.x & 63;
  const int lr = lane & 15, q = lane >> 4;
  const int panel = blockIdx.x;                  // 0..2047
  const int row   = panel * 16 + lr;
  const float* tr = p_tar + (size_t)row * NCLS;
  const float* vr = p_vlm + (size_t)row * NCLS;
  u16* a4 = (u16*)A4 + (size_t)panel * NCH * 512 + lane * 8;

  float bvT = -1.0f; int biT = 0;
  float bvV = -1.0f; int biV = 0;
  for (int c = w * 8; c < w * 8 + 8; ++c) {
    const int k0 = c * 32 + q * 8;
    float v[8];
    if (k0 < NCLS) {
      float4 x = *(const float4*)(tr + k0);
      float4 y = *(const float4*)(tr + k0 + 4);
      v[0] = x.x; v[1] = x.y; v[2] = x.z; v[3] = x.w;
      v[4] = y.x; v[5] = y.y; v[6] = y.z; v[7] = y.w;
    } else {
      #pragma unroll
      for (int j = 0; j < 8; ++j) v[j] = 0.0f;
    }
    bf16x8 o;
    #pragma unroll
    for (int j = 0; j < 8; ++j) {
      o[j] = (__bf16)v[j];
      if (v[j] > bvT) { bvT = v[j]; biT = k0 + j; }
    }
    *(bf16x8*)(a4 + (size_t)c * 512) = o;
    if (k0 < NCLS) {
      float4 x = *(const float4*)(vr + k0);
      float4 y = *(const float4*)(vr + k0 + 4);
      float u[8] = {x.x, x.y, x.z, x.w, y.x, y.y, y.z, y.w};
      #pragma unroll
      for (int j = 0; j < 8; ++j)
        if (u[j] > bvV) { bvV = u[j]; biV = k0 + j; }
    }
  }
  // reduce across the 4 q-lanes owning row lr (xor 16, 32), first-occurrence ties
  #pragma unroll
  for (int d = 16; d < 64; d <<= 1) {
    float ov = __shfl_xor(bvT, d); int oi = __shfl_xor(biT, d);
    if (ov > bvT || (ov == bvT && oi < biT)) { bvT = ov; biT = oi; }
    float ov2 = __shfl_xor(bvV, d); int oi2 = __shfl_xor(biV, d);
    if (ov2 > bvV || (ov2 == bvV && oi2 < biV)) { bvV = ov2; biV = oi2; }
  }
  if (q == 0) { sT[w][lr] = bvT; siT[w][lr] = biT; sV[w][lr] = bvV; siV[w][lr] = biV; }
  __syncthreads();
  // combine k-quarters (all lanes: row lr), ascending w => strict > keeps min index
  float cT = sT[0][lr]; int ciT = siT[0][lr];
  float cV = sV[0][lr]; int ciV = siV[0][lr];
  #pragma unroll
  for (int ww = 1; ww < 4; ++ww) {
    float v1 = sT[ww][lr]; if (v1 > cT) { cT = v1; ciT = siT[ww][lr]; }
    float v2 = sV[ww][lr]; if (v2 > cV) { cV = v2; ciV = siV[ww][lr]; }
  }
  if (w == 0) {                                  // rare (~B/NCLS rows agree)
    const int ag = (ciT == ciV) ? 1 : 0;
    for (int rr = 0; rr < 16; ++rr) {
      const int agr = __shfl(ag, rr);
      if (agr) {                                 // wave-uniform
        const int cls = __shfl(ciT, rr);
        const float* trr = p_tar + (size_t)(panel * 16 + rr) * NCLS;
        for (int k = lane; k < NCLS; k += 64)
          atomicAdd(&sums[(size_t)cls * NCLS + k], trr[k]);
        if (lane == 0) atomicAdd(&counts[cls], 1.0f);
      }
    }
  }
}

// ---- fragment-chunk MFMA GEMM, depth-2 prefetch (3 LDS buffers) + counted vmcnt.
// At iter i: wait vmcnt(4) [own oldest 4 loads = buf cur done; 4 newer stay in
// flight], raw s_barrier (collective), stage iter i+2. Prefetch distance = 2
// iterations (~700-800 cyc) -> covers L2(200)/L3/cross-XCD(~600)/most-HBM(900)
// latency that the 1-deep vmcnt(0)-drain schedule exposed. Only the peeled
// last iteration drains to vmcnt(0). Loop has no other VMEM ops, so the
// per-wave vmcnt FIFO counting is exact (4 gld_lds per stage).
// Block mapping: xcd = L&7 (round-robin dispatch->XCD), bn fastest WITHIN an
// XCD -> A-tile fetched from HBM once per 8 consecutive same-XCD blocks.
// WHICH==1: E4 = frag-chunk bf16 exp(norm*S) (cols>=1000 -> 0) + atomic rowsum
// WHICH==2: p_mix row-major f32
template <int WHICH>
__global__ __launch_bounds__(256, 3)
void gemm4(const u16* __restrict__ A4, const u16* __restrict__ B4,
           __hip_bfloat16* __restrict__ E4out, float* __restrict__ rowsum,
           const float* __restrict__ p_vlm, float* __restrict__ mix_out) {
  __shared__ u16 SH[6][4096];   // [0..2]=A tri-buf; [3..5]=B tri-buf; 48KB; epi uses [0..3]
  const int tid  = threadIdx.x;
  const int w    = tid >> 6;
  const int lane = tid & 63;
  const int lr   = lane & 15;
  const int q    = lane >> 4;
  const int L    = blockIdx.x;                    // 0..2047
  const int xcd  = L & 7;
  const int jj   = L >> 3;                        // 0..255 within-XCD dispatch order
  const int bm   = xcd * 32 + (jj >> 3);          // 0..255; 8 consecutive jj share bm
  const int bn   = jj & 7;                        // 0..7 fastest within XCD
  const int wm   = w >> 1;
  const int wn   = w & 1;

  f32x4 acc[4][4] = {};

  // wave w stages A panels {2w,2w+1} and B panels {2w,2w+1} of the block's 8
  const u16* ga0 = A4 + ((size_t)(bm * 8 + 2 * w) * NCH) * 512 + lane * 8;
  const u16* ga1 = ga0 + (size_t)NCH * 512;
  const u16* gb0 = B4 + ((size_t)(bn * 8 + 2 * w) * NCH) * 512 + lane * 8;
  const u16* gb1 = gb0 + (size_t)NCH * 512;

  // stage k-chunk kk into buffer slot b (4 gld_lds per wave, program order)
  #define STAGE4(kk, b)                                            \
    do {                                                           \
      const size_t ko = (size_t)(kk) * 512;                        \
      gld_lds16(ga0 + ko, &SH[(b)][(2 * w + 0) * 512]);            \
      gld_lds16(ga1 + ko, &SH[(b)][(2 * w + 1) * 512]);            \
      gld_lds16(gb0 + ko, &SH[3 + (b)][(2 * w + 0) * 512]);        \
      gld_lds16(gb1 + ko, &SH[3 + (b)][(2 * w + 1) * 512]);        \
    } while (0)

  STAGE4(0, 0);
  STAGE4(1, 1);

  int cur = 0;
  for (int i = 0; i < NCH; ++i) {
    if (i < NCH - 1) {
      asm volatile("s_waitcnt vmcnt(4)" ::: "memory");   // cur's 4 done, next 4 in flight
    } else {
      asm volatile("s_waitcnt vmcnt(0)" ::: "memory");   // peeled tail: full drain
    }
    __builtin_amdgcn_s_barrier();                        // raw: no compiler drain
    asm volatile("" ::: "memory");                       // fence ds_reads below barrier
    if (i + 2 < NCH) {
      int b2 = cur + 2; if (b2 >= 3) b2 -= 3;
      STAGE4(i + 2, b2);
    }
    bf16x8 af[4], bfr[4];
    #pragma unroll
    for (int t = 0; t < 4; ++t) {
      af[t]  = *(const bf16x8*)(&SH[cur][(wm * 4 + t) * 512 + lane * 8]);
      bfr[t] = *(const bf16x8*)(&SH[3 + cur][(wn * 4 + t) * 512 + lane * 8]);
    }
    #pragma unroll
    for (int mt = 0; mt < 4; ++mt)
      #pragma unroll
      for (int nt = 0; nt < 4; ++nt)
        acc[mt][nt] = __builtin_amdgcn_mfma_f32_16x16x32_bf16(af[mt], bfr[nt], acc[mt][nt], 0, 0, 0);
    cur = (cur == 2) ? 0 : cur + 1;
  }
  #undef STAGE4

  const float NORM = 0.03162277660168379f;  // 1/sqrt(1000)
  if (WHICH == 1) {
    __syncthreads();                 // LDS now reusable for epilogue bounce
    u16* ep = &SH[w][0];             // 8KB per-wave private region (SH[0..3])
    #pragma unroll
    for (int mt = 0; mt < 4; ++mt) {
      float psum[4] = {0.f, 0.f, 0.f, 0.f};
      #pragma unroll
      for (int nt = 0; nt < 4; ++nt) {
        const int gn = bn * 128 + wn * 64 + nt * 16 + lr;
        const int cc = nt >> 1;                      // chunk within wave (0..1)
        const int q2 = (nt & 1) * 2 + (lr >> 3);     // k-subchunk in chunk
        const int jj2 = lr & 7;
        #pragma unroll
        for (int r = 0; r < 4; ++r) {
          float e = (gn < NCLS) ? __expf(acc[mt][nt][r] * NORM) : 0.0f;
          psum[r] += e;
          __hip_bfloat16 h = __float2bfloat16(e);
          ep[(mt * 2 + cc) * 512 + (q2 * 16 + q * 4 + r) * 8 + jj2] = *(u16*)&h;
        }
      }
      #pragma unroll
      for (int r = 0; r < 4; ++r) {
        float s = psum[r];
        s += __shfl_xor(s, 1); s += __shfl_xor(s, 2);
        s += __shfl_xor(s, 4); s += __shfl_xor(s, 8);
        if (lr == 0) atomicAdd(&rowsum[bm * 128 + wm * 64 + mt * 16 + q * 4 + r], s);
      }
    }
    #pragma unroll
    for (int ch = 0; ch < 8; ++ch) {   // coalesced 1KB flushes
      const int mt = ch >> 1, cc = ch & 1;
      bf16x8 v = *(const bf16x8*)(&ep[ch * 512 + lane * 8]);
      const size_t Rg = bm * 8 + wm * 4 + mt;
      const size_t cg = bn * 4 + wn * 2 + cc;
      *(bf16x8*)((u16*)E4out + (Rg * NCH + cg) * 512 + lane * 8) = v;
    }
  } else {
    #pragma unroll
    for (int mt = 0; mt < 4; ++mt) {
      #pragma unroll
      for (int r = 0; r < 4; ++r) {
        const int gm = bm * 128 + wm * 64 + mt * 16 + q * 4 + r;
        const float inv = 1.0f / rowsum[gm];
        #pragma unroll
        for (int nt = 0; nt < 4; ++nt) {
          const int gn = bn * 128 + wn * 64 + nt * 16 + lr;
          if (gn < NCLS) {
            float pt = acc[mt][nt][r] * inv;                 // p_tar_new
            float pv = p_vlm[(size_t)gm * NCLS + gn];
            // p_mix = (et*pt+ev*pv)/(et+ev) with r=ev/et: one exp instead of two
            float lt = pt * __logf(pt + 1e-6f);
            float lv = pv * __logf(pv + 1e-6f);
            float rr = __expf(lv - lt);
            mix_out[(size_t)gm * NCLS + gn] = (pt + rr * pv) / (1.0f + rr);
          }
        }
      }
    }
  }
}

// ---- bank EMA update
__global__ __launch_bounds__(256)
void bank_update(const float* __restrict__ bank, const float* __restrict__ sums,
                 const float* __restrict__ counts, const float* __restrict__ alpha,
                 float* __restrict__ out) {
  const int idx = blockIdx.x * 256 + threadIdx.x;
  if (idx >= NCLS * NCLS) return;
  const int r = idx / NCLS;
  const float cnt = counts[r];
  const float bv  = bank[idx];
  const float a   = alpha[0];
  out[idx] = (cnt > 0.0f) ? a * bv + (1.0f - a) * (sums[idx] / cnt) : bv;
}

extern "C" void kernel_launch(void* const* d_in, const int* in_sizes, int n_in,
                              void* d_out, int out_size, void* d_ws, size_t ws_size,
                              hipStream_t stream) {
  const float* p_tar = (const float*)d_in[0];
  const float* p_vlm = (const float*)d_in[1];
  const float* alpha = (const float*)d_in[2];
  const float* bank  = (const float*)d_in[3];
  float* out_mix  = (float*)d_out;                         // [32768*1000]
  float* out_bank = (float*)d_out + (size_t)NROWS * NCLS;  // [1000*1000]

  char* w = (char*)d_ws;
  __hip_bfloat16* A4  = (__hip_bfloat16*)w; w += (size_t)NROWS * KP * 2;  // 64 MB
  __hip_bfloat16* E4  = (__hip_bfloat16*)w; w += (size_t)NROWS * KP * 2;  // 64 MB
  __hip_bfloat16* M4  = (__hip_bfloat16*)w; w += (size_t)KP * KP * 2;     // 2 MB
  __hip_bfloat16* MT4 = (__hip_bfloat16*)w; w += (size_t)KP * KP * 2;     // 2 MB
  float* sums   = (float*)w;                w += (size_t)NCLS * NCLS * 4; // 4 MB
  float* counts = (float*)w;                w += 1024 * 4;
  float* rs     = (float*)w;                w += (size_t)NROWS * 4;

  // zero atomic accumulators: sums + counts + rs are contiguous
  hipMemsetAsync(sums, 0, (size_t)NCLS * NCLS * 4 + 1024 * 4 + (size_t)NROWS * 4, stream);

  prep4_bank<<<dim3(32, 32), 128, 0, stream>>>(bank, M4, MT4);
  rows4_kernel<<<NROWS / 16, 256, 0, stream>>>(p_tar, p_vlm, A4, sums, counts);
  gemm4<1><<<2048, 256, 0, stream>>>(
      (const u16*)A4, (const u16*)M4, E4, rs, nullptr, nullptr);
  gemm4<2><<<2048, 256, 0, stream>>>(
      (const u16*)E4, (const u16*)MT4, nullptr, rs, p_vlm, out_mix);
  bank_update<<<(NCLS * NCLS + 255) / 256, 256, 0, stream>>>(bank, sums, counts, alpha, out_bank);
}